// Round 1
// baseline (1297.074 us; speedup 1.0000x reference)
//
#include <hip/hip_runtime.h>
#include <math.h>

#define IN_DIM 256
#define OUT_DIM 64
#define NEG_SLOPE 0.2f

// ---------------------------------------------------------------------------
// K1: per-node  h = x @ W  (one wave per node, lane = output column)
//     also s_src[n] = h[n]·a[:64], s_dst[n] = h[n]·a[64:], denom[n]=0,
//     and zero d_out.
// W (256x64 f32 = 64 KB) staged in LDS; x row kept in 4 regs/lane and
// broadcast with __shfl (wave-uniform readlane).
// ---------------------------------------------------------------------------
__global__ __launch_bounds__(256) void k1_gemm_scores(
        const float* __restrict__ x, const float* __restrict__ W,
        const float* __restrict__ a, float* __restrict__ h,
        float* __restrict__ s_src, float* __restrict__ s_dst,
        float* __restrict__ denom, float* __restrict__ out, int N)
{
    __shared__ float w_lds[IN_DIM * OUT_DIM];   // 65536 B (== static limit)

    const int tid = threadIdx.x;
    // stage W: 16384 floats = 4096 float4, 256 threads -> 16 each, coalesced
    for (int i = tid; i < (IN_DIM * OUT_DIM) / 4; i += 256)
        ((float4*)w_lds)[i] = ((const float4*)W)[i];
    __syncthreads();

    const int lane = tid & 63;
    const int wv   = tid >> 6;
    const float a_s = a[lane];
    const float a_d = a[OUT_DIM + lane];

    const int gw = blockIdx.x * 4 + wv;       // global wave id
    const int nw = gridDim.x * 4;             // total waves

    for (int n = gw; n < N; n += nw) {
        const float* xr = x + (size_t)n * IN_DIM;
        // x row -> 4 regs per lane (coalesced 256B loads)
        float xv0 = xr[lane];
        float xv1 = xr[lane + 64];
        float xv2 = xr[lane + 128];
        float xv3 = xr[lane + 192];

        float acc = 0.f;
        #pragma unroll
        for (int j = 0; j < 4; ++j) {
            float xvj = (j == 0) ? xv0 : (j == 1) ? xv1 : (j == 2) ? xv2 : xv3;
            #pragma unroll
            for (int l = 0; l < 64; ++l) {
                float xk = __shfl(xvj, l, 64);          // wave-uniform broadcast
                acc = fmaf(xk, w_lds[(j * 64 + l) * OUT_DIM + lane], acc);
            }
        }

        h[(size_t)n * OUT_DIM + lane]  = acc;
        out[(size_t)n * OUT_DIM + lane] = 0.f;          // zero output accumulator

        // two wave reductions (s_src, s_dst) interleaved
        float rs = acc * a_s;
        float rd = acc * a_d;
        #pragma unroll
        for (int off = 32; off > 0; off >>= 1) {
            rs += __shfl_xor(rs, off, 64);
            rd += __shfl_xor(rd, off, 64);
        }
        if (lane == 0) {
            s_src[n] = rs;
            s_dst[n] = rd;
            denom[n] = 0.f;
        }
    }
}

// ---------------------------------------------------------------------------
// K2: per-edge (one wave per edge).  Softmax max-shift skipped: it is
// mathematically a no-op (shift invariance) and e is bounded (~|e|<1.5),
// so exp cannot overflow.  Accumulate UNNORMALIZED: out[dst] += ex*h[src],
// denom[dst] += ex.  Normalization happens in K3.
// ---------------------------------------------------------------------------
__global__ __launch_bounds__(256) void k2_edges(
        const int* __restrict__ ei, const float* __restrict__ h,
        const float* __restrict__ s_src, const float* __restrict__ s_dst,
        float* __restrict__ denom, float* __restrict__ out, int E)
{
    const int lane = threadIdx.x & 63;
    const int gw   = (blockIdx.x * blockDim.x + threadIdx.x) >> 6;
    const int nw   = (gridDim.x * blockDim.x) >> 6;

    for (int e = gw; e < E; e += nw) {
        const int src = ei[e];
        const int dst = ei[E + e];
        float sc = s_src[src] + s_dst[dst];
        sc = (sc > 0.f) ? sc : NEG_SLOPE * sc;          // LeakyReLU
        const float ex = __expf(sc);

        if (lane == 0) atomicAdd(&denom[dst], ex);

        const float hv = h[(size_t)src * OUT_DIM + lane];   // coalesced 256B gather
        atomicAdd(&out[(size_t)dst * OUT_DIM + lane], hv * ex);
    }
}

// ---------------------------------------------------------------------------
// K3: out[n,:] /= denom[n]  (in place, float4).  denom==0 -> 0 (empty segment).
// ---------------------------------------------------------------------------
__global__ __launch_bounds__(256) void k3_normalize(
        float* __restrict__ out, const float* __restrict__ denom, int nvec4)
{
    int i = blockIdx.x * blockDim.x + threadIdx.x;
    const int strd = gridDim.x * blockDim.x;
    for (; i < nvec4; i += strd) {
        const float d = denom[i >> 4];                  // 16 float4 per node row
        float4 v = ((float4*)out)[i];
        if (d != 0.f) {
            const float r = 1.f / d;
            v.x *= r; v.y *= r; v.z *= r; v.w *= r;
        } else {
            v.x = v.y = v.z = v.w = 0.f;
        }
        ((float4*)out)[i] = v;
    }
}

extern "C" void kernel_launch(void* const* d_in, const int* in_sizes, int n_in,
                              void* d_out, int out_size, void* d_ws, size_t ws_size,
                              hipStream_t stream)
{
    const float* x  = (const float*)d_in[0];
    const float* W  = (const float*)d_in[1];
    const float* a  = (const float*)d_in[2];
    const int*   ei = (const int*)d_in[3];

    const int N = in_sizes[0] / IN_DIM;     // 100000
    const int E = in_sizes[3] / 2;          // 1600000

    float* out    = (float*)d_out;
    float* h      = (float*)d_ws;                       // N*64 f32 = 25.6 MB
    float* s_src  = h + (size_t)N * OUT_DIM;            // N f32
    float* s_dst  = s_src + N;                          // N f32
    float* denom  = s_dst + N;                          // N f32

    k1_gemm_scores<<<2048, 256, 0, stream>>>(x, W, a, h, s_src, s_dst, denom, out, N);
    k2_edges<<<4096, 256, 0, stream>>>(ei, h, s_src, s_dst, denom, out, E);
    k3_normalize<<<2048, 256, 0, stream>>>(out, denom, (N * OUT_DIM) / 4);
}

// Round 2
// 496.174 us; speedup vs baseline: 2.6142x; 2.6142x over previous
//
#include <hip/hip_runtime.h>
#include <hip/hip_bf16.h>
#include <math.h>

#define IN_DIM 256
#define OUT_DIM 64
#define NEG_SLOPE 0.2f

typedef __attribute__((ext_vector_type(8))) short bf16x8;
typedef __attribute__((ext_vector_type(4))) float f32x4;

static __device__ __forceinline__ ushort f2bf(float f) {
    union { __hip_bfloat16 b; ushort u; } cv;
    cv.b = __float2bfloat16(f);          // RNE convert
    return cv.u;
}
static __device__ __forceinline__ float bf2f(ushort u) {
    union { ushort u2[2]; float f; } cv;
    cv.u2[0] = 0; cv.u2[1] = u;
    return cv.f;
}

// ---------------------------------------------------------------------------
// K1: h = x @ W via bf16 MFMA (16x16x32). One wave per 16-node group.
//   A (x rows): loaded global->reg directly in fragment layout, coalesced.
//   B (W):      staged once/block into LDS, pre-swizzled so each lane's
//               8 bf16 are contiguous (ds_read_b128, conflict-free).
//   Fragment layouts (gfx950 mfma_f32_16x16x32_bf16):
//     A[i][k]: lane = 16*(k/8) + i, elem = k%8
//     B[k][j]: lane = 16*(k/8) + j, elem = k%8
//     D[i][j]: lane = 16*(i/4) + j, reg  = i%4
//   Epilogue fuses s_src = h.a[:64], s_dst = h.a[64:] (16-lane reductions)
//   and stores h as bf16 for K2's gather.
// ---------------------------------------------------------------------------
__global__ __launch_bounds__(256) void k1_mfma(
        const float* __restrict__ x, const float* __restrict__ W,
        const float* __restrict__ a, ushort* __restrict__ hb,
        float* __restrict__ s_src, float* __restrict__ s_dst,
        int N, int ngroups)
{
    // W_swz[t][khi][col][j], t=k-tile(8), khi=lane>>4(4), col(64), j(8) : 32 KB
    __shared__ ushort w_lds[8 * 4 * 64 * 8];

    const int tid = threadIdx.x;
    for (int idx = tid; idx < 16384; idx += 256) {
        const int j   = idx & 7;
        const int col = (idx >> 3) & 63;
        const int khi = (idx >> 9) & 3;
        const int t   = idx >> 11;
        const int k   = t * 32 + khi * 8 + j;
        w_lds[idx] = f2bf(W[k * OUT_DIM + col]);
    }
    __syncthreads();

    const int lane = tid & 63;
    const int l15  = lane & 15;
    const int khi  = lane >> 4;

    float a_s[4], a_d[4];
    #pragma unroll
    for (int c = 0; c < 4; ++c) {
        a_s[c] = a[c * 16 + l15];
        a_d[c] = a[OUT_DIM + c * 16 + l15];
    }

    const int gw = blockIdx.x * 4 + (tid >> 6);
    const int nw = gridDim.x * 4;

    for (int g = gw; g < ngroups; g += nw) {
        const int node    = g * 16 + l15;
        const int node_ld = (node < N) ? node : (N - 1);
        const float* xp = x + (size_t)node_ld * IN_DIM + khi * 8;

        // A fragments: 8 k-tiles, each 8 consecutive f32 -> bf16x8
        bf16x8 af[8];
        #pragma unroll
        for (int t = 0; t < 8; ++t) {
            float4 lo = *(const float4*)(xp + t * 32);
            float4 hi = *(const float4*)(xp + t * 32 + 4);
            union { bf16x8 v; ushort u[8]; } pk;
            pk.u[0] = f2bf(lo.x); pk.u[1] = f2bf(lo.y);
            pk.u[2] = f2bf(lo.z); pk.u[3] = f2bf(lo.w);
            pk.u[4] = f2bf(hi.x); pk.u[5] = f2bf(hi.y);
            pk.u[6] = f2bf(hi.z); pk.u[7] = f2bf(hi.w);
            af[t] = pk.v;
        }

        f32x4 acc[4] = {{0,0,0,0},{0,0,0,0},{0,0,0,0},{0,0,0,0}};
        #pragma unroll
        for (int t = 0; t < 8; ++t) {
            const bf16x8* wp = (const bf16x8*)w_lds + (t * 4 + khi) * 64 + l15;
            #pragma unroll
            for (int c = 0; c < 4; ++c)
                acc[c] = __builtin_amdgcn_mfma_f32_16x16x32_bf16(
                             af[t], wp[c * 16], acc[c], 0, 0, 0);
        }

        // epilogue: store h (bf16), fused per-node scores
        const int row0 = g * 16 + khi * 4;
        #pragma unroll
        for (int r = 0; r < 4; ++r) {
            const int nrow = row0 + r;
            float rs = 0.f, rd = 0.f;
            #pragma unroll
            for (int c = 0; c < 4; ++c) {
                const float v = acc[c][r];
                if (nrow < N)
                    hb[(size_t)nrow * OUT_DIM + c * 16 + l15] = f2bf(v);
                rs = fmaf(v, a_s[c], rs);
                rd = fmaf(v, a_d[c], rd);
            }
            #pragma unroll
            for (int off = 1; off < 16; off <<= 1) {   // reduce across 16 cols
                rs += __shfl_xor(rs, off, 64);
                rd += __shfl_xor(rd, off, 64);
            }
            if (l15 == 0 && nrow < N) {
                s_src[nrow] = rs;
                s_dst[nrow] = rd;
            }
        }
    }
}

// ---------------------------------------------------------------------------
// K2: per-edge (one wave per edge). Softmax max-shift skipped (shift-invariant,
// |e| bounded so exp can't overflow). Unnormalized accumulation:
//   out[dst,:] += ex * h[src,:]   (f32 atomics), denom[dst] += ex.
// h gathered as bf16 (halved traffic vs f32).
// ---------------------------------------------------------------------------
__global__ __launch_bounds__(256) void k2_edges(
        const int* __restrict__ ei, const ushort* __restrict__ hb,
        const float* __restrict__ s_src, const float* __restrict__ s_dst,
        float* __restrict__ denom, float* __restrict__ out, int E)
{
    const int lane = threadIdx.x & 63;
    const int gw   = (blockIdx.x * blockDim.x + threadIdx.x) >> 6;
    const int nw   = (gridDim.x * blockDim.x) >> 6;

    for (int e = gw; e < E; e += nw) {
        const int src = ei[e];
        const int dst = ei[E + e];
        float sc = s_src[src] + s_dst[dst];
        sc = (sc > 0.f) ? sc : NEG_SLOPE * sc;          // LeakyReLU
        const float ex = __expf(sc);

        if (lane == 0) atomicAdd(&denom[dst], ex);

        const float hv = bf2f(hb[(size_t)src * OUT_DIM + lane]);
        atomicAdd(&out[(size_t)dst * OUT_DIM + lane], hv * ex);
    }
}

// ---------------------------------------------------------------------------
// K3: out[n,:] /= denom[n]  (in place, float4). denom==0 -> 0 (empty segment).
// ---------------------------------------------------------------------------
__global__ __launch_bounds__(256) void k3_normalize(
        float* __restrict__ out, const float* __restrict__ denom, int nvec4)
{
    int i = blockIdx.x * blockDim.x + threadIdx.x;
    const int strd = gridDim.x * blockDim.x;
    for (; i < nvec4; i += strd) {
        const float d = denom[i >> 4];                  // 16 float4 per node row
        float4 v = ((float4*)out)[i];
        if (d != 0.f) {
            const float r = 1.f / d;
            v.x *= r; v.y *= r; v.z *= r; v.w *= r;
        } else {
            v.x = v.y = v.z = v.w = 0.f;
        }
        ((float4*)out)[i] = v;
    }
}

extern "C" void kernel_launch(void* const* d_in, const int* in_sizes, int n_in,
                              void* d_out, int out_size, void* d_ws, size_t ws_size,
                              hipStream_t stream)
{
    const float* x  = (const float*)d_in[0];
    const float* W  = (const float*)d_in[1];
    const float* a  = (const float*)d_in[2];
    const int*   ei = (const int*)d_in[3];

    const int N = in_sizes[0] / IN_DIM;     // 100000
    const int E = in_sizes[3] / 2;          // 1600000

    float*  out   = (float*)d_out;
    ushort* hb    = (ushort*)d_ws;                       // N*64 bf16 = 12.8 MB
    float*  s_src = (float*)(hb + (size_t)N * OUT_DIM);  // N f32
    float*  s_dst = s_src + N;                           // N f32
    float*  denom = s_dst + N;                           // N f32

    hipMemsetAsync(out,   0, (size_t)out_size * sizeof(float), stream);
    hipMemsetAsync(denom, 0, (size_t)N * sizeof(float), stream);

    const int ngroups = (N + 15) / 16;                   // 6250
    const int k1_blocks = (ngroups + 3) / 4;             // 4 waves/block
    k1_mfma<<<k1_blocks, 256, 0, stream>>>(x, W, a, hb, s_src, s_dst, N, ngroups);
    k2_edges<<<4096, 256, 0, stream>>>(ei, hb, s_src, s_dst, denom, out, E);
    k3_normalize<<<2048, 256, 0, stream>>>(out, denom, (N * OUT_DIM) / 4);
}

// Round 3
// 370.209 us; speedup vs baseline: 3.5036x; 1.3403x over previous
//
#include <hip/hip_runtime.h>
#include <hip/hip_bf16.h>
#include <math.h>

#define IN_DIM 256
#define OUT_DIM 64
#define NEG_SLOPE 0.2f

typedef __attribute__((ext_vector_type(8))) short bf16x8;
typedef __attribute__((ext_vector_type(4))) float f32x4;

static __device__ __forceinline__ ushort f2bf(float f) {
    union { __hip_bfloat16 b; ushort u; } cv;
    cv.b = __float2bfloat16(f);
    return cv.u;
}
static __device__ __forceinline__ float bf2f(ushort u) {
    union { ushort u2[2]; float f; } cv;
    cv.u2[0] = 0; cv.u2[1] = u;
    return cv.f;
}

// ---------------------------------------------------------------------------
// K1: h = x @ W via bf16 MFMA 16x16x32 (unchanged from R2 — ~40us).
// ---------------------------------------------------------------------------
__global__ __launch_bounds__(256) void k1_mfma(
        const float* __restrict__ x, const float* __restrict__ W,
        const float* __restrict__ a, ushort* __restrict__ hb,
        float* __restrict__ s_src, float* __restrict__ s_dst,
        int N, int ngroups)
{
    __shared__ ushort w_lds[8 * 4 * 64 * 8];   // 32 KB, fragment-swizzled

    const int tid = threadIdx.x;
    for (int idx = tid; idx < 16384; idx += 256) {
        const int j   = idx & 7;
        const int col = (idx >> 3) & 63;
        const int khi = (idx >> 9) & 3;
        const int t   = idx >> 11;
        const int k   = t * 32 + khi * 8 + j;
        w_lds[idx] = f2bf(W[k * OUT_DIM + col]);
    }
    __syncthreads();

    const int lane = tid & 63;
    const int l15  = lane & 15;
    const int khi  = lane >> 4;

    float a_s[4], a_d[4];
    #pragma unroll
    for (int c = 0; c < 4; ++c) {
        a_s[c] = a[c * 16 + l15];
        a_d[c] = a[OUT_DIM + c * 16 + l15];
    }

    const int gw = blockIdx.x * 4 + (tid >> 6);
    const int nw = gridDim.x * 4;

    for (int g = gw; g < ngroups; g += nw) {
        const int node    = g * 16 + l15;
        const int node_ld = (node < N) ? node : (N - 1);
        const float* xp = x + (size_t)node_ld * IN_DIM + khi * 8;

        bf16x8 af[8];
        #pragma unroll
        for (int t = 0; t < 8; ++t) {
            float4 lo = *(const float4*)(xp + t * 32);
            float4 hi = *(const float4*)(xp + t * 32 + 4);
            union { bf16x8 v; ushort u[8]; } pk;
            pk.u[0] = f2bf(lo.x); pk.u[1] = f2bf(lo.y);
            pk.u[2] = f2bf(lo.z); pk.u[3] = f2bf(lo.w);
            pk.u[4] = f2bf(hi.x); pk.u[5] = f2bf(hi.y);
            pk.u[6] = f2bf(hi.z); pk.u[7] = f2bf(hi.w);
            af[t] = pk.v;
        }

        f32x4 acc[4] = {{0,0,0,0},{0,0,0,0},{0,0,0,0},{0,0,0,0}};
        #pragma unroll
        for (int t = 0; t < 8; ++t) {
            const bf16x8* wp = (const bf16x8*)w_lds + (t * 4 + khi) * 64 + l15;
            #pragma unroll
            for (int c = 0; c < 4; ++c)
                acc[c] = __builtin_amdgcn_mfma_f32_16x16x32_bf16(
                             af[t], wp[c * 16], acc[c], 0, 0, 0);
        }

        const int row0 = g * 16 + khi * 4;
        #pragma unroll
        for (int r = 0; r < 4; ++r) {
            const int nrow = row0 + r;
            float rs = 0.f, rd = 0.f;
            #pragma unroll
            for (int c = 0; c < 4; ++c) {
                const float v = acc[c][r];
                if (nrow < N)
                    hb[(size_t)nrow * OUT_DIM + c * 16 + l15] = f2bf(v);
                rs = fmaf(v, a_s[c], rs);
                rd = fmaf(v, a_d[c], rd);
            }
            #pragma unroll
            for (int off = 1; off < 16; off <<= 1) {
                rs += __shfl_xor(rs, off, 64);
                rd += __shfl_xor(rd, off, 64);
            }
            if (l15 == 0 && nrow < N) {
                s_src[nrow] = rs;
                s_dst[nrow] = rd;
            }
        }
    }
}

// ---------------------------------------------------------------------------
// CSR build: hist -> 3-kernel exclusive scan -> scatter.
// ---------------------------------------------------------------------------
__global__ __launch_bounds__(256) void k_hist(
        const int* __restrict__ dst, int* __restrict__ cursor, int E)
{
    int i = blockIdx.x * blockDim.x + threadIdx.x;
    const int strd = gridDim.x * blockDim.x;
    for (; i < E; i += strd)
        atomicAdd(&cursor[dst[i]], 1);
}

// block-level exclusive scan of counts -> base (exclusive within block),
// block total -> partials[blockIdx]
__global__ __launch_bounds__(256) void k_scan_block(
        const int* __restrict__ counts, int* __restrict__ base,
        int* __restrict__ partials, int N)
{
    const int t = threadIdx.x;
    const int i = blockIdx.x * 256 + t;
    const int lane = t & 63, wv = t >> 6;
    int v = (i < N) ? counts[i] : 0;
    int s = v;
    #pragma unroll
    for (int off = 1; off < 64; off <<= 1) {
        int u = __shfl_up(s, off, 64);
        if (lane >= off) s += u;
    }
    __shared__ int wsum[4];
    if (lane == 63) wsum[wv] = s;
    __syncthreads();
    if (t == 0) {
        int acc = 0;
        #pragma unroll
        for (int j = 0; j < 4; ++j) { int tmp = wsum[j]; wsum[j] = acc; acc += tmp; }
        partials[blockIdx.x] = acc;
    }
    __syncthreads();
    const int excl = s - v + wsum[wv];
    if (i < N) base[i] = excl;
}

// exclusive scan of partials (<=512) in a single block
__global__ __launch_bounds__(512) void k_scan_part(int* __restrict__ partials, int NB)
{
    const int t = threadIdx.x;
    const int lane = t & 63, wv = t >> 6;
    int v = (t < NB) ? partials[t] : 0;
    int s = v;
    #pragma unroll
    for (int off = 1; off < 64; off <<= 1) {
        int u = __shfl_up(s, off, 64);
        if (lane >= off) s += u;
    }
    __shared__ int wsum[8];
    if (lane == 63) wsum[wv] = s;
    __syncthreads();
    if (t == 0) {
        int acc = 0;
        #pragma unroll
        for (int j = 0; j < 8; ++j) { int tmp = wsum[j]; wsum[j] = acc; acc += tmp; }
    }
    __syncthreads();
    const int excl = s - v + wsum[wv];
    if (t < NB) partials[t] = excl;
}

// base += scanned block offset; cursor = base; base[N] = E
__global__ __launch_bounds__(256) void k_scan_add(
        int* __restrict__ base, const int* __restrict__ partials,
        int* __restrict__ cursor, int N, int E)
{
    const int i = blockIdx.x * 256 + threadIdx.x;
    if (i < N) {
        const int b = base[i] + partials[blockIdx.x];
        base[i] = b;
        cursor[i] = b;
    }
    if (i == 0) base[N] = E;
}

__global__ __launch_bounds__(256) void k_scatter(
        const int* __restrict__ ei, int* __restrict__ cursor,
        int* __restrict__ csr, int E)
{
    int i = blockIdx.x * blockDim.x + threadIdx.x;
    const int strd = gridDim.x * blockDim.x;
    for (; i < E; i += strd) {
        const int src = ei[i];
        const int dst = ei[E + i];
        const int pos = atomicAdd(&cursor[dst], 1);
        csr[pos] = src;
    }
}

// ---------------------------------------------------------------------------
// K2: one wave per dst node. Lane j holds edge j's (src, ex); wave-reduce
// denom; shfl-broadcast loop gathers h rows and FMAs into registers.
// Normalization fused -> single plain store. No atomics.
// ---------------------------------------------------------------------------
__global__ __launch_bounds__(256) void k2_gather(
        const int* __restrict__ csr, const int* __restrict__ base,
        const ushort* __restrict__ hb, const float* __restrict__ s_src,
        const float* __restrict__ s_dst, float* __restrict__ out, int N)
{
    const int w = (blockIdx.x * 256 + threadIdx.x) >> 6;
    if (w >= N) return;
    const int lane = threadIdx.x & 63;

    const int beg = base[w];
    const int end = base[w + 1];
    const float sd = s_dst[w];

    float acc = 0.f, den = 0.f;
    for (int b = beg; b < end; b += 64) {
        const int cnt = min(64, end - b);
        int   srcj = 0;
        float exj  = 0.f;
        if (lane < cnt) {
            srcj = csr[b + lane];
            float sc = s_src[srcj] + sd;
            sc = (sc > 0.f) ? sc : NEG_SLOPE * sc;
            exj = __expf(sc);
        }
        float t = exj;
        #pragma unroll
        for (int off = 1; off < 64; off <<= 1)
            t += __shfl_xor(t, off, 64);
        den += t;

        for (int j = 0; j < cnt; ++j) {
            const int   s  = __shfl(srcj, j, 64);
            const float ex = __shfl(exj,  j, 64);
            acc = fmaf(ex, bf2f(hb[(size_t)s * OUT_DIM + lane]), acc);
        }
    }
    out[(size_t)w * OUT_DIM + lane] = (end > beg) ? acc / den : 0.f;
}

extern "C" void kernel_launch(void* const* d_in, const int* in_sizes, int n_in,
                              void* d_out, int out_size, void* d_ws, size_t ws_size,
                              hipStream_t stream)
{
    const float* x  = (const float*)d_in[0];
    const float* W  = (const float*)d_in[1];
    const float* a  = (const float*)d_in[2];
    const int*   ei = (const int*)d_in[3];

    const int N = in_sizes[0] / IN_DIM;     // 100000
    const int E = in_sizes[3] / 2;          // 1600000

    float* out = (float*)d_out;

    // workspace layout (~20.8 MB)
    char* ws = (char*)d_ws;
    ushort* hb     = (ushort*)ws;                  ws += (size_t)N * OUT_DIM * 2; // 12.8 MB
    float*  s_src  = (float*)ws;                   ws += (size_t)N * 4;
    float*  s_dst  = (float*)ws;                   ws += (size_t)N * 4;
    int*    base   = (int*)ws;                     ws += (size_t)(N + 1) * 4;
    int*    cursor = (int*)ws;                     ws += (size_t)N * 4;
    int*    parts  = (int*)ws;                     ws += 512 * 4;
    int*    csr    = (int*)ws;                     ws += (size_t)E * 4;           // 6.4 MB

    const int NB = (N + 255) / 256;                // scan blocks (391)

    hipMemsetAsync(cursor, 0, (size_t)N * 4, stream);

    // CSR build
    k_hist<<<2048, 256, 0, stream>>>(ei + E, cursor, E);
    k_scan_block<<<NB, 256, 0, stream>>>(cursor, base, parts, N);
    k_scan_part<<<1, 512, 0, stream>>>(parts, NB);
    k_scan_add<<<NB, 256, 0, stream>>>(base, parts, cursor, N, E);
    k_scatter<<<2048, 256, 0, stream>>>(ei, cursor, csr, E);

    // node GEMM + scores
    const int ngroups = (N + 15) / 16;
    k1_mfma<<<(ngroups + 3) / 4, 256, 0, stream>>>(x, W, a, hb, s_src, s_dst, N, ngroups);

    // fused gather + softmax-normalize
    k2_gather<<<(N + 3) / 4, 256, 0, stream>>>(csr, base, hb, s_src, s_dst, out, N);
}

// Round 4
// 256.004 us; speedup vs baseline: 5.0666x; 1.4461x over previous
//
#include <hip/hip_runtime.h>
#include <hip/hip_bf16.h>
#include <math.h>

#define IN_DIM 256
#define OUT_DIM 64
#define NEG_SLOPE 0.2f

typedef __attribute__((ext_vector_type(8))) short bf16x8;
typedef __attribute__((ext_vector_type(4))) float f32x4;

static __device__ __forceinline__ ushort f2bf(float f) {
    union { __hip_bfloat16 b; ushort u; } cv;
    cv.b = __float2bfloat16(f);
    return cv.u;
}
static __device__ __forceinline__ float bf2f(ushort u) {
    union { ushort u2[2]; float f; } cv;
    cv.u2[0] = 0; cv.u2[1] = u;
    return cv.f;
}

// ---------------------------------------------------------------------------
// K1: h = x @ W via bf16 MFMA 16x16x32 (unchanged — ~40us).
// ---------------------------------------------------------------------------
__global__ __launch_bounds__(256) void k1_mfma(
        const float* __restrict__ x, const float* __restrict__ W,
        const float* __restrict__ a, ushort* __restrict__ hb,
        float* __restrict__ s_src, float* __restrict__ s_dst,
        int N, int ngroups)
{
    __shared__ ushort w_lds[8 * 4 * 64 * 8];   // 32 KB, fragment-swizzled

    const int tid = threadIdx.x;
    for (int idx = tid; idx < 16384; idx += 256) {
        const int j   = idx & 7;
        const int col = (idx >> 3) & 63;
        const int khi = (idx >> 9) & 3;
        const int t   = idx >> 11;
        const int k   = t * 32 + khi * 8 + j;
        w_lds[idx] = f2bf(W[k * OUT_DIM + col]);
    }
    __syncthreads();

    const int lane = tid & 63;
    const int l15  = lane & 15;
    const int khi  = lane >> 4;

    float a_s[4], a_d[4];
    #pragma unroll
    for (int c = 0; c < 4; ++c) {
        a_s[c] = a[c * 16 + l15];
        a_d[c] = a[OUT_DIM + c * 16 + l15];
    }

    const int gw = blockIdx.x * 4 + (tid >> 6);
    const int nw = gridDim.x * 4;

    for (int g = gw; g < ngroups; g += nw) {
        const int node    = g * 16 + l15;
        const int node_ld = (node < N) ? node : (N - 1);
        const float* xp = x + (size_t)node_ld * IN_DIM + khi * 8;

        bf16x8 af[8];
        #pragma unroll
        for (int t = 0; t < 8; ++t) {
            float4 lo = *(const float4*)(xp + t * 32);
            float4 hi = *(const float4*)(xp + t * 32 + 4);
            union { bf16x8 v; ushort u[8]; } pk;
            pk.u[0] = f2bf(lo.x); pk.u[1] = f2bf(lo.y);
            pk.u[2] = f2bf(lo.z); pk.u[3] = f2bf(lo.w);
            pk.u[4] = f2bf(hi.x); pk.u[5] = f2bf(hi.y);
            pk.u[6] = f2bf(hi.z); pk.u[7] = f2bf(hi.w);
            af[t] = pk.v;
        }

        f32x4 acc[4] = {{0,0,0,0},{0,0,0,0},{0,0,0,0},{0,0,0,0}};
        #pragma unroll
        for (int t = 0; t < 8; ++t) {
            const bf16x8* wp = (const bf16x8*)w_lds + (t * 4 + khi) * 64 + l15;
            #pragma unroll
            for (int c = 0; c < 4; ++c)
                acc[c] = __builtin_amdgcn_mfma_f32_16x16x32_bf16(
                             af[t], wp[c * 16], acc[c], 0, 0, 0);
        }

        const int row0 = g * 16 + khi * 4;
        #pragma unroll
        for (int r = 0; r < 4; ++r) {
            const int nrow = row0 + r;
            float rs = 0.f, rd = 0.f;
            #pragma unroll
            for (int c = 0; c < 4; ++c) {
                const float v = acc[c][r];
                if (nrow < N)
                    hb[(size_t)nrow * OUT_DIM + c * 16 + l15] = f2bf(v);
                rs = fmaf(v, a_s[c], rs);
                rd = fmaf(v, a_d[c], rd);
            }
            #pragma unroll
            for (int off = 1; off < 16; off <<= 1) {
                rs += __shfl_xor(rs, off, 64);
                rd += __shfl_xor(rd, off, 64);
            }
            if (l15 == 0 && nrow < N) {
                s_src[nrow] = rs;
                s_dst[nrow] = rd;
            }
        }
    }
}

// ---------------------------------------------------------------------------
// CSR build: hist -> 3-kernel exclusive scan -> chunked scatter.
// ---------------------------------------------------------------------------
__global__ __launch_bounds__(256) void k_hist(
        const int* __restrict__ dst, int* __restrict__ cursor, int E)
{
    int i = blockIdx.x * blockDim.x + threadIdx.x;
    const int strd = gridDim.x * blockDim.x;
    for (; i < E; i += strd)
        atomicAdd(&cursor[dst[i]], 1);
}

__global__ __launch_bounds__(256) void k_scan_block(
        const int* __restrict__ counts, int* __restrict__ base,
        int* __restrict__ partials, int N)
{
    const int t = threadIdx.x;
    const int i = blockIdx.x * 256 + t;
    const int lane = t & 63, wv = t >> 6;
    int v = (i < N) ? counts[i] : 0;
    int s = v;
    #pragma unroll
    for (int off = 1; off < 64; off <<= 1) {
        int u = __shfl_up(s, off, 64);
        if (lane >= off) s += u;
    }
    __shared__ int wsum[4];
    if (lane == 63) wsum[wv] = s;
    __syncthreads();
    if (t == 0) {
        int acc = 0;
        #pragma unroll
        for (int j = 0; j < 4; ++j) { int tmp = wsum[j]; wsum[j] = acc; acc += tmp; }
        partials[blockIdx.x] = acc;
    }
    __syncthreads();
    const int excl = s - v + wsum[wv];
    if (i < N) base[i] = excl;
}

__global__ __launch_bounds__(512) void k_scan_part(int* __restrict__ partials, int NB)
{
    const int t = threadIdx.x;
    const int lane = t & 63, wv = t >> 6;
    int v = (t < NB) ? partials[t] : 0;
    int s = v;
    #pragma unroll
    for (int off = 1; off < 64; off <<= 1) {
        int u = __shfl_up(s, off, 64);
        if (lane >= off) s += u;
    }
    __shared__ int wsum[8];
    if (lane == 63) wsum[wv] = s;
    __syncthreads();
    if (t == 0) {
        int acc = 0;
        #pragma unroll
        for (int j = 0; j < 8; ++j) { int tmp = wsum[j]; wsum[j] = acc; acc += tmp; }
    }
    __syncthreads();
    const int excl = s - v + wsum[wv];
    if (t < NB) partials[t] = excl;
}

__global__ __launch_bounds__(256) void k_scan_add(
        int* __restrict__ base, const int* __restrict__ partials,
        int* __restrict__ cursor, int N, int E)
{
    const int i = blockIdx.x * 256 + threadIdx.x;
    if (i < N) {
        const int b = base[i] + partials[blockIdx.x];
        base[i] = b;
        cursor[i] = b;
    }
    if (i == 0) base[N] = E;
}

// Chunked scatter: block b owns dst-chunk (b&7) [~0.8 MB csr region, fits one
// XCD L2] and edge-slice (b>>3). With round-robin block->XCD mapping, all
// writers of a chunk share one XCD -> dirty lines survive until full ->
// ~1 HBM write per line instead of ~16. Slice re-reads served by LLC.
__global__ __launch_bounds__(256) void k_scatter8(
        const int* __restrict__ ei, int* __restrict__ cursor,
        int* __restrict__ csr, int E, int chunk_n)
{
    const int c  = blockIdx.x & 7;
    const int g  = blockIdx.x >> 3;
    const int ng = gridDim.x >> 3;
    const int lo = c * chunk_n, hi = lo + chunk_n;
    const int e0 = (int)(((long long)g * E) / ng);
    const int e1 = (int)(((long long)(g + 1) * E) / ng);
    for (int i = e0 + threadIdx.x; i < e1; i += 256) {
        const int dst = ei[E + i];
        if (dst >= lo && dst < hi) {
            const int pos = atomicAdd(&cursor[dst], 1);
            csr[pos] = ei[i];
        }
    }
}

// ---------------------------------------------------------------------------
// K2: one wave per dst node. Batch of 64 edges held one-per-lane (src, ex).
// Inner loop: 4 edges/iteration — quarter-wave q handles edge it*4+q, each
// lane loads ushort4 (4 cols). Cross-quarter shfl_xor(16/32) combine, lanes
// 0-15 store float4. Normalization fused; no atomics.
// ---------------------------------------------------------------------------
__global__ __launch_bounds__(256) void k2_gather(
        const int* __restrict__ csr, const int* __restrict__ base,
        const ushort* __restrict__ hb, const float* __restrict__ s_src,
        const float* __restrict__ s_dst, float* __restrict__ out, int N)
{
    const int w = (blockIdx.x * 256 + threadIdx.x) >> 6;
    if (w >= N) return;
    const int lane = threadIdx.x & 63;
    const int l15  = lane & 15;
    const int q    = lane >> 4;

    const int beg = base[w];
    const int end = base[w + 1];
    const float sd = s_dst[w];

    float acc[4] = {0.f, 0.f, 0.f, 0.f};
    float den = 0.f;

    for (int b = beg; b < end; b += 64) {
        const int cnt = min(64, end - b);
        int   srcj = 0;
        float exj  = 0.f;
        if (lane < cnt) {
            srcj = csr[b + lane];
            float sc = s_src[srcj] + sd;
            sc = (sc > 0.f) ? sc : NEG_SLOPE * sc;
            exj = __expf(sc);
        }
        float t = exj;
        #pragma unroll
        for (int off = 1; off < 64; off <<= 1)
            t += __shfl_xor(t, off, 64);
        den += t;

        const int iters = (cnt + 3) >> 2;
        for (int it = 0; it < iters; ++it) {
            const int j = it * 4 + q;                      // edge idx in batch
            const int   s  = __shfl(srcj, j, 64);          // j<64 always
            const float ex = __shfl(exj,  j, 64);          // 0 for j>=cnt
            const ushort4 hv = *(const ushort4*)(hb + ((size_t)s << 6) + (l15 << 2));
            acc[0] = fmaf(ex, bf2f(hv.x), acc[0]);
            acc[1] = fmaf(ex, bf2f(hv.y), acc[1]);
            acc[2] = fmaf(ex, bf2f(hv.z), acc[2]);
            acc[3] = fmaf(ex, bf2f(hv.w), acc[3]);
        }
    }

    #pragma unroll
    for (int k = 0; k < 4; ++k) {
        acc[k] += __shfl_xor(acc[k], 16, 64);
        acc[k] += __shfl_xor(acc[k], 32, 64);
    }
    if (lane < 16) {
        const float r = (end > beg) ? 1.f / den : 0.f;
        float4 v;
        v.x = acc[0] * r; v.y = acc[1] * r; v.z = acc[2] * r; v.w = acc[3] * r;
        *(float4*)(out + ((size_t)w << 6) + (l15 << 2)) = v;
    }
}

extern "C" void kernel_launch(void* const* d_in, const int* in_sizes, int n_in,
                              void* d_out, int out_size, void* d_ws, size_t ws_size,
                              hipStream_t stream)
{
    const float* x  = (const float*)d_in[0];
    const float* W  = (const float*)d_in[1];
    const float* a  = (const float*)d_in[2];
    const int*   ei = (const int*)d_in[3];

    const int N = in_sizes[0] / IN_DIM;     // 100000
    const int E = in_sizes[3] / 2;          // 1600000

    float* out = (float*)d_out;

    char* ws = (char*)d_ws;
    ushort* hb     = (ushort*)ws;                  ws += (size_t)N * OUT_DIM * 2; // 12.8 MB
    float*  s_src  = (float*)ws;                   ws += (size_t)N * 4;
    float*  s_dst  = (float*)ws;                   ws += (size_t)N * 4;
    int*    base   = (int*)ws;                     ws += (size_t)(N + 1) * 4;
    int*    cursor = (int*)ws;                     ws += (size_t)N * 4;
    int*    parts  = (int*)ws;                     ws += 512 * 4;
    int*    csr    = (int*)ws;                     ws += (size_t)E * 4;           // 6.4 MB

    const int NB = (N + 255) / 256;
    const int chunk_n = (N + 7) / 8;               // 12500 dsts per chunk

    hipMemsetAsync(cursor, 0, (size_t)N * 4, stream);

    k_hist<<<2048, 256, 0, stream>>>(ei + E, cursor, E);
    k_scan_block<<<NB, 256, 0, stream>>>(cursor, base, parts, N);
    k_scan_part<<<1, 512, 0, stream>>>(parts, NB);
    k_scan_add<<<NB, 256, 0, stream>>>(base, parts, cursor, N, E);
    k_scatter8<<<2048, 256, 0, stream>>>(ei, cursor, csr, E, chunk_n);

    const int ngroups = (N + 15) / 16;
    k1_mfma<<<(ngroups + 3) / 4, 256, 0, stream>>>(x, W, a, hb, s_src, s_dst, N, ngroups);

    k2_gather<<<(N + 3) / 4, 256, 0, stream>>>(csr, base, hb, s_src, s_dst, out, N);
}

// Round 5
// 233.371 us; speedup vs baseline: 5.5580x; 1.0970x over previous
//
#include <hip/hip_runtime.h>
#include <hip/hip_bf16.h>
#include <math.h>

#define IN_DIM 256
#define OUT_DIM 64
#define NEG_SLOPE 0.2f
#define LCOLS 80   // 64 h-cols + 16-col score tile (col64=Wa_s, col65=Wa_d)

typedef __attribute__((ext_vector_type(8))) short bf16x8;
typedef __attribute__((ext_vector_type(4))) float f32x4;

static __device__ __forceinline__ ushort f2bf(float f) {
    union { __hip_bfloat16 b; ushort u; } cv;
    cv.b = __float2bfloat16(f);
    return cv.u;
}
static __device__ __forceinline__ float bf2f(ushort u) {
    union { ushort u2[2]; float f; } cv;
    cv.u2[0] = 0; cv.u2[1] = u;
    return cv.f;
}

// ---------------------------------------------------------------------------
// k0_wa: Wa_s[k] = sum_j W[k][j]*a[j], Wa_d[k] = sum_j W[k][j]*a[64+j].
// One block, 256 threads (one per k).
// ---------------------------------------------------------------------------
__global__ __launch_bounds__(256) void k0_wa(
        const float* __restrict__ W, const float* __restrict__ a,
        float* __restrict__ wa)
{
    const int k = threadIdx.x;
    const float* wr = W + (size_t)k * OUT_DIM;
    float ss = 0.f, sd = 0.f;
    #pragma unroll
    for (int j = 0; j < OUT_DIM; ++j) {
        const float w = wr[j];
        ss = fmaf(w, a[j], ss);
        sd = fmaf(w, a[OUT_DIM + j], sd);
    }
    wa[k] = ss;
    wa[IN_DIM + k] = sd;
}

// ---------------------------------------------------------------------------
// k0_swz: build pre-swizzled bf16 B-tile in global (8t x 4khi x 80col x 8j).
// cols 0-63 = W, col 64 = Wa_s, col 65 = Wa_d, 66-79 = 0.  20480 elems.
// ---------------------------------------------------------------------------
__global__ __launch_bounds__(256) void k0_swz(
        const float* __restrict__ W, const float* __restrict__ wa,
        ushort* __restrict__ wb)
{
    const int idx = blockIdx.x * 256 + threadIdx.x;
    const int j   = idx & 7;
    const int col = (idx >> 3) % LCOLS;
    const int tk  = (idx >> 3) / LCOLS;          // t*4 + khi, 0..31
    const int k   = (tk >> 2) * 32 + (tk & 3) * 8 + j;
    float v = 0.f;
    if (col < OUT_DIM)           v = W[(size_t)k * OUT_DIM + col];
    else if (col == OUT_DIM)     v = wa[k];
    else if (col == OUT_DIM + 1) v = wa[IN_DIM + k];
    wb[idx] = f2bf(v);
}

// ---------------------------------------------------------------------------
// K1: h = x @ W via bf16 MFMA 16x16x32, scores fused as B-columns 64/65.
// 512 blocks (2/CU), grid-stride ~3 groups/wave, register-double-buffered
// x prefetch. LDS B-tile copied from pre-swizzled global (no per-block cvt).
// ---------------------------------------------------------------------------
__global__ __launch_bounds__(256) void k1_mfma(
        const float* __restrict__ x, const ushort* __restrict__ wb,
        ushort* __restrict__ hb, float* __restrict__ s_src,
        float* __restrict__ s_dst, int N, int ngroups)
{
    __shared__ ushort w_lds[8 * 4 * LCOLS * 8];          // 40960 B

    const int tid = threadIdx.x;
    for (int i = tid; i < (8 * 4 * LCOLS * 8) / 8; i += 256)   // 2560 float4
        ((float4*)w_lds)[i] = ((const float4*)wb)[i];
    __syncthreads();

    const int lane = tid & 63;
    const int l15  = lane & 15;
    const int khi  = lane >> 4;

    const int gw = blockIdx.x * 4 + (tid >> 6);
    const int nw = gridDim.x * 4;

    float4 raw[16];
    int g = gw;
    if (g < ngroups) {
        const int node = min(g * 16 + l15, N - 1);
        const float* xp = x + (size_t)node * IN_DIM + khi * 8;
        #pragma unroll
        for (int t = 0; t < 8; ++t) {
            raw[2 * t]     = *(const float4*)(xp + t * 32);
            raw[2 * t + 1] = *(const float4*)(xp + t * 32 + 4);
        }
    }

    for (; g < ngroups; g += nw) {
        // convert current raw -> bf16 fragments
        bf16x8 af[8];
        #pragma unroll
        for (int t = 0; t < 8; ++t) {
            union { bf16x8 v; ushort u[8]; } pk;
            pk.u[0] = f2bf(raw[2*t].x);   pk.u[1] = f2bf(raw[2*t].y);
            pk.u[2] = f2bf(raw[2*t].z);   pk.u[3] = f2bf(raw[2*t].w);
            pk.u[4] = f2bf(raw[2*t+1].x); pk.u[5] = f2bf(raw[2*t+1].y);
            pk.u[6] = f2bf(raw[2*t+1].z); pk.u[7] = f2bf(raw[2*t+1].w);
            af[t] = pk.v;
        }

        // prefetch next group's x (overlaps with MFMAs below)
        const int gn = g + nw;
        if (gn < ngroups) {
            const int node = min(gn * 16 + l15, N - 1);
            const float* xp = x + (size_t)node * IN_DIM + khi * 8;
            #pragma unroll
            for (int t = 0; t < 8; ++t) {
                raw[2 * t]     = *(const float4*)(xp + t * 32);
                raw[2 * t + 1] = *(const float4*)(xp + t * 32 + 4);
            }
        }

        f32x4 acc[5] = {{0,0,0,0},{0,0,0,0},{0,0,0,0},{0,0,0,0},{0,0,0,0}};
        #pragma unroll
        for (int t = 0; t < 8; ++t) {
            const bf16x8* wp = (const bf16x8*)w_lds + (t * 4 + khi) * LCOLS + l15;
            #pragma unroll
            for (int c = 0; c < 5; ++c)
                acc[c] = __builtin_amdgcn_mfma_f32_16x16x32_bf16(
                             af[t], wp[c * 16], acc[c], 0, 0, 0);
        }

        const int row0 = g * 16 + khi * 4;
        #pragma unroll
        for (int r = 0; r < 4; ++r) {
            const int nrow = row0 + r;
            if (nrow < N) {
                #pragma unroll
                for (int c = 0; c < 4; ++c)
                    hb[(size_t)nrow * OUT_DIM + c * 16 + l15] = f2bf(acc[c][r]);
                if (l15 == 0) s_src[nrow] = acc[4][r];   // score-tile col 0
                if (l15 == 1) s_dst[nrow] = acc[4][r];   // score-tile col 1
            }
        }
    }
}

// ---------------------------------------------------------------------------
// CSR build: hist -> 3-kernel exclusive scan -> chunked scatter (with fused
// per-edge attention weight ex = exp(leakyrelu(s_src[src]+s_dst[dst]))).
// ---------------------------------------------------------------------------
__global__ __launch_bounds__(256) void k_hist(
        const int* __restrict__ dst, int* __restrict__ cursor, int E)
{
    int i = blockIdx.x * blockDim.x + threadIdx.x;
    const int strd = gridDim.x * blockDim.x;
    for (; i < E; i += strd)
        atomicAdd(&cursor[dst[i]], 1);
}

__global__ __launch_bounds__(256) void k_scan_block(
        const int* __restrict__ counts, int* __restrict__ base,
        int* __restrict__ partials, int N)
{
    const int t = threadIdx.x;
    const int i = blockIdx.x * 256 + t;
    const int lane = t & 63, wv = t >> 6;
    int v = (i < N) ? counts[i] : 0;
    int s = v;
    #pragma unroll
    for (int off = 1; off < 64; off <<= 1) {
        int u = __shfl_up(s, off, 64);
        if (lane >= off) s += u;
    }
    __shared__ int wsum[4];
    if (lane == 63) wsum[wv] = s;
    __syncthreads();
    if (t == 0) {
        int acc = 0;
        #pragma unroll
        for (int j = 0; j < 4; ++j) { int tmp = wsum[j]; wsum[j] = acc; acc += tmp; }
        partials[blockIdx.x] = acc;
    }
    __syncthreads();
    const int excl = s - v + wsum[wv];
    if (i < N) base[i] = excl;
}

__global__ __launch_bounds__(512) void k_scan_part(int* __restrict__ partials, int NB)
{
    const int t = threadIdx.x;
    const int lane = t & 63, wv = t >> 6;
    int v = (t < NB) ? partials[t] : 0;
    int s = v;
    #pragma unroll
    for (int off = 1; off < 64; off <<= 1) {
        int u = __shfl_up(s, off, 64);
        if (lane >= off) s += u;
    }
    __shared__ int wsum[8];
    if (lane == 63) wsum[wv] = s;
    __syncthreads();
    if (t == 0) {
        int acc = 0;
        #pragma unroll
        for (int j = 0; j < 8; ++j) { int tmp = wsum[j]; wsum[j] = acc; acc += tmp; }
    }
    __syncthreads();
    const int excl = s - v + wsum[wv];
    if (t < NB) partials[t] = excl;
}

__global__ __launch_bounds__(256) void k_scan_add(
        int* __restrict__ base, const int* __restrict__ partials,
        int* __restrict__ cursor, int N, int E)
{
    const int i = blockIdx.x * 256 + threadIdx.x;
    if (i < N) {
        const int b = base[i] + partials[blockIdx.x];
        base[i] = b;
        cursor[i] = b;
    }
    if (i == 0) base[N] = E;
}

// Chunked scatter (dst-chunk per XCD-slot, write footprint 1.6 MB -> L2-fits).
// Fuses the edge score: csr2[pos] = {src, bits(exp(lrelu(s_src+s_dst)))}.
__global__ __launch_bounds__(256) void k_scatter8(
        const int* __restrict__ ei, const float* __restrict__ s_src,
        const float* __restrict__ s_dst, int* __restrict__ cursor,
        int2* __restrict__ csr2, int E, int chunk_n)
{
    const int c  = blockIdx.x & 7;
    const int g  = blockIdx.x >> 3;
    const int ng = gridDim.x >> 3;
    const int lo = c * chunk_n, hi = lo + chunk_n;
    const int e0 = (int)(((long long)g * E) / ng);
    const int e1 = (int)(((long long)(g + 1) * E) / ng);
    for (int i = e0 + threadIdx.x; i < e1; i += 256) {
        const int dst = ei[E + i];
        if (dst >= lo && dst < hi) {
            const int src = ei[i];
            float sc = s_src[src] + s_dst[dst];
            sc = (sc > 0.f) ? sc : NEG_SLOPE * sc;
            const int pos = atomicAdd(&cursor[dst], 1);
            csr2[pos] = make_int2(src, __float_as_int(__expf(sc)));
        }
    }
}

// ---------------------------------------------------------------------------
// K2: quarter-wave (16 lanes) per dst node, 4 nodes/wave, 16 nodes/block.
// Scoring phase = one coalesced 8B load/lane (ex precomputed in scatter),
// 4-step den reduce; inner loop broadcasts (src,ex) and FMAs ushort4 h-rows.
// ---------------------------------------------------------------------------
__global__ __launch_bounds__(256) void k2_gather(
        const int2* __restrict__ csr2, const int* __restrict__ base,
        const ushort* __restrict__ hb, float* __restrict__ out, int N)
{
    const int w = blockIdx.x * 16 + (threadIdx.x >> 4);
    if (w >= N) return;
    const int l15   = threadIdx.x & 15;
    const int qbase = threadIdx.x & 48;      // this quarter's base lane in wave

    const int beg = base[w];
    const int end = base[w + 1];

    float a0 = 0.f, a1 = 0.f, a2 = 0.f, a3 = 0.f, den = 0.f;

    for (int b = beg; b < end; b += 16) {
        const int cnt = min(16, end - b);
        int   srcj = 0;
        float exj  = 0.f;
        if (l15 < cnt) {
            const int2 p = csr2[b + l15];
            srcj = p.x;
            exj  = __int_as_float(p.y);
        }
        float t = exj;
        t += __shfl_xor(t, 1, 64);
        t += __shfl_xor(t, 2, 64);
        t += __shfl_xor(t, 4, 64);
        t += __shfl_xor(t, 8, 64);
        den += t;

        for (int j = 0; j < cnt; ++j) {
            const int   s  = __shfl(srcj, qbase + j, 64);
            const float ex = __shfl(exj,  qbase + j, 64);
            const ushort4 hv = *(const ushort4*)(hb + ((size_t)s << 6) + (l15 << 2));
            a0 = fmaf(ex, bf2f(hv.x), a0);
            a1 = fmaf(ex, bf2f(hv.y), a1);
            a2 = fmaf(ex, bf2f(hv.z), a2);
            a3 = fmaf(ex, bf2f(hv.w), a3);
        }
    }

    const float r = (end > beg) ? 1.f / den : 0.f;
    float4 v;
    v.x = a0 * r; v.y = a1 * r; v.z = a2 * r; v.w = a3 * r;
    *(float4*)(out + ((size_t)w << 6) + (l15 << 2)) = v;
}

extern "C" void kernel_launch(void* const* d_in, const int* in_sizes, int n_in,
                              void* d_out, int out_size, void* d_ws, size_t ws_size,
                              hipStream_t stream)
{
    const float* x  = (const float*)d_in[0];
    const float* W  = (const float*)d_in[1];
    const float* a  = (const float*)d_in[2];
    const int*   ei = (const int*)d_in[3];

    const int N = in_sizes[0] / IN_DIM;     // 100000
    const int E = in_sizes[3] / 2;          // 1600000

    float* out = (float*)d_out;

    char* ws = (char*)d_ws;
    ushort* hb     = (ushort*)ws;                  ws += (size_t)N * OUT_DIM * 2; // 12.8 MB
    float*  s_src  = (float*)ws;                   ws += (size_t)N * 4;
    float*  s_dst  = (float*)ws;                   ws += (size_t)N * 4;
    int*    base   = (int*)ws;                     ws += (size_t)(N + 1) * 4;
    int*    cursor = (int*)ws;                     ws += (size_t)N * 4;
    int*    parts  = (int*)ws;                     ws += 512 * 4;
    float*  wa     = (float*)ws;                   ws += 2 * IN_DIM * 4;
    ushort* wb     = (ushort*)ws;                  ws += 8 * 4 * LCOLS * 8 * 2;   // 40 KB
    int2*   csr2   = (int2*)ws;                    ws += (size_t)E * 8;           // 12.8 MB

    const int NB = (N + 255) / 256;
    const int chunk_n = (N + 7) / 8;

    hipMemsetAsync(cursor, 0, (size_t)N * 4, stream);

    // CSR counts + offsets (independent of GEMM)
    k_hist<<<2048, 256, 0, stream>>>(ei + E, cursor, E);
    k_scan_block<<<NB, 256, 0, stream>>>(cursor, base, parts, N);
    k_scan_part<<<1, 512, 0, stream>>>(parts, NB);
    k_scan_add<<<NB, 256, 0, stream>>>(base, parts, cursor, N, E);

    // node GEMM with fused score columns
    k0_wa<<<1, 256, 0, stream>>>(W, a, wa);
    k0_swz<<<(8 * 4 * LCOLS * 8) / 256, 256, 0, stream>>>(W, wa, wb);
    const int ngroups = (N + 15) / 16;
    k1_mfma<<<512, 256, 0, stream>>>(x, wb, hb, s_src, s_dst, N, ngroups);

    // scatter with fused edge weights, then gather
    k_scatter8<<<2048, 256, 0, stream>>>(ei, s_src, s_dst, cursor, csr2, E, chunk_n);
    k2_gather<<<(N + 15) / 16, 256, 0, stream>>>(csr2, base, hb, out, N);
}